// Round 8
// baseline (66106.000 us; speedup 1.0000x reference)
//
#include <hip/hip_runtime.h>
#include <float.h>

#define KC 4096
#define DIM 256
#define MB 16384            // m per batch element (16*32*32)
#define NTOT 65536          // rows
#define ZELEMS 16777216
#define LOSS_OFF 16777216
#define IDX_OFF  16777217
#define TAU 4.5e-5f         // window: > ULP(512)=3.05e-5 + 2*eps + slack
#define FULL_SENTINEL 33554432.0f   // 2^25, exact in f32

// merge (top1, top2, cnt) lexicographically by (value, index).
// The losing champion is window-checked here (cross-lane competitor count).
__device__ __forceinline__ void merge2(float& b1, int& i1, float& b2, int& i2, int& cnt,
                                       float ob1, int oi1, float ob2, int oi2, int ocnt) {
    cnt += ocnt;
    bool ow = (ob1 < b1) || (ob1 == b1 && oi1 < i1);
    float w1v = ow ? ob1 : b1;  int w1i = ow ? oi1 : i1;
    float l1v = ow ? b1 : ob1;  int l1i = ow ? i1 : oi1;   // losing champion
    if (l1v <= w1v + TAU) cnt++;
    float w2v = ow ? ob2 : b2;  int w2i = ow ? oi2 : i2;
    bool s2 = (w2v < l1v) || (w2v == l1v && w2i < l1i);
    b1 = w1v; i1 = w1i;
    b2 = s2 ? w2v : l1v; i2 = s2 ? w2i : l1i;
}

// ---- K1: f32 fast pass. Block = 128 rows; 32-code chunks staged [d][code].
// Flags are encoded IN-BAND into out[IDX_OFF+row]:
//   cnt==0 : plain I1 (0..4095)                      -> final
//   cnt==1 : -(I1 + 4096*I2 + 1)  (exact, <=2^24)    -> pair rescore
//   cnt>=2 : 2^25                                    -> full rescan
__global__ __launch_bounds__(256) void vq_fast(const float* __restrict__ z,
                                               const float* __restrict__ e,
                                               float* __restrict__ out) {
    __shared__ float lds_ep[DIM][34];
    __shared__ float mb1[4][128], mb2[4][128];
    __shared__ int   mi1[4][128], mi2[4][128], mcnt[4][128];

    const int tid = threadIdx.x;
    const int wave = tid >> 6, lane = tid & 63;
    const int l16 = lane & 15, g = lane >> 4;
    const int nbase = blockIdx.x * 128;
    const int b = nbase / MB;
    const int mbase = nbase % MB;
    const float* zb = z + (size_t)b * DIM * MB;
    const int mrow = mbase + 4 * l16;
    const int cw = wave * 8 + g * 2;

    float b1[8], b2[8];
    int i1[8], i2[8], cnt[8];
    #pragma unroll
    for (int i = 0; i < 8; ++i) { b1[i] = FLT_MAX; b2[i] = FLT_MAX; i1[i] = 0; i2[i] = 0; cnt[i] = 0; }

    for (int chunk = 0; chunk < KC / 32; ++chunk) {
        const int cbase = chunk * 32;
        {   // stage 32 codes x 256 d, transposed to [d][code]
            const float4* src = reinterpret_cast<const float4*>(e + (size_t)cbase * DIM);
            #pragma unroll
            for (int i = 0; i < 8; ++i) {
                int f = tid + 256 * i;
                int code = f >> 6;
                int dw = (f & 63) * 4;
                float4 v = src[f];
                lds_ep[dw][code] = v.x; lds_ep[dw + 1][code] = v.y;
                lds_ep[dw + 2][code] = v.z; lds_ep[dw + 3][code] = v.w;
            }
        }
        __syncthreads();

        // |e|^2 (fp64 -> f32) for this lane's 2 codes, coop across 16 lanes
        double cs0 = 0.0, cs1 = 0.0;
        #pragma unroll
        for (int dd = 0; dd < 16; ++dd) {
            float a0 = lds_ep[l16 * 16 + dd][cw];
            float a1 = lds_ep[l16 * 16 + dd][cw + 1];
            cs0 += (double)a0 * a0;
            cs1 += (double)a1 * a1;
        }
        #pragma unroll
        for (int m = 1; m < 16; m <<= 1) { cs0 += __shfl_xor(cs0, m); cs1 += __shfl_xor(cs1, m); }
        const float bf0 = (float)cs0, bf1 = (float)cs1;

        float acc[8][2];
        #pragma unroll
        for (int i = 0; i < 8; ++i) { acc[i][0] = 0.f; acc[i][1] = 0.f; }

        #pragma unroll 4
        for (int d = 0; d < DIM; ++d) {
            const float2 ep = *reinterpret_cast<const float2*>(&lds_ep[d][cw]);
            float4 za = *reinterpret_cast<const float4*>(zb + (size_t)d * MB + mrow);
            float4 zc = *reinterpret_cast<const float4*>(zb + (size_t)d * MB + mrow + 64);
            acc[0][0] = fmaf(za.x, ep.x, acc[0][0]); acc[0][1] = fmaf(za.x, ep.y, acc[0][1]);
            acc[1][0] = fmaf(za.y, ep.x, acc[1][0]); acc[1][1] = fmaf(za.y, ep.y, acc[1][1]);
            acc[2][0] = fmaf(za.z, ep.x, acc[2][0]); acc[2][1] = fmaf(za.z, ep.y, acc[2][1]);
            acc[3][0] = fmaf(za.w, ep.x, acc[3][0]); acc[3][1] = fmaf(za.w, ep.y, acc[3][1]);
            acc[4][0] = fmaf(zc.x, ep.x, acc[4][0]); acc[4][1] = fmaf(zc.x, ep.y, acc[4][1]);
            acc[5][0] = fmaf(zc.y, ep.x, acc[5][0]); acc[5][1] = fmaf(zc.y, ep.y, acc[5][1]);
            acc[6][0] = fmaf(zc.z, ep.x, acc[6][0]); acc[6][1] = fmaf(zc.z, ep.y, acc[6][1]);
            acc[7][0] = fmaf(zc.w, ep.x, acc[7][0]); acc[7][1] = fmaf(zc.w, ep.y, acc[7][1]);
        }

        const int k0 = cbase + cw;
        #pragma unroll
        for (int i = 0; i < 8; ++i) {
            #pragma unroll
            for (int c = 0; c < 2; ++c) {
                float s = fmaf(-2.0f, acc[i][c], c ? bf1 : bf0);
                int k = k0 + c;
                if (s < b1[i]) {
                    if (b1[i] <= s + TAU) cnt[i]++;       // displaced champion in window
                    b2[i] = b1[i]; i2[i] = i1[i];
                    b1[i] = s; i1[i] = k;
                } else {
                    if (s <= b1[i] + TAU) cnt[i]++;       // conservative (stale-min) count
                    if (s < b2[i]) { b2[i] = s; i2[i] = k; }
                }
            }
        }
        __syncthreads();
    }

    // merge across the 4 g-groups (xor 16, 32)
    #pragma unroll
    for (int off = 16; off < 64; off <<= 1) {
        #pragma unroll
        for (int i = 0; i < 8; ++i) {
            float ob1 = __shfl_xor(b1[i], off), ob2 = __shfl_xor(b2[i], off);
            int oi1 = __shfl_xor(i1[i], off), oi2 = __shfl_xor(i2[i], off);
            int oc = __shfl_xor(cnt[i], off);
            merge2(b1[i], i1[i], b2[i], i2[i], cnt[i], ob1, oi1, ob2, oi2, oc);
        }
    }
    if (g == 0) {
        #pragma unroll
        for (int i = 0; i < 8; ++i) {
            int r = (i < 4) ? (4 * l16 + i) : (64 + 4 * l16 + (i - 4));
            mb1[wave][r] = b1[i]; mb2[wave][r] = b2[i];
            mi1[wave][r] = i1[i]; mi2[wave][r] = i2[i]; mcnt[wave][r] = cnt[i];
        }
    }
    __syncthreads();
    if (tid < 128) {
        float B1 = mb1[0][tid], B2 = mb2[0][tid];
        int I1 = mi1[0][tid], I2 = mi2[0][tid], C = mcnt[0][tid];
        #pragma unroll
        for (int wv = 1; wv < 4; ++wv)
            merge2(B1, I1, B2, I2, C, mb1[wv][tid], mi1[wv][tid], mb2[wv][tid], mi2[wv][tid], mcnt[wv][tid]);
        float enc;
        if (C == 0)      enc = (float)I1;
        else if (C == 1) enc = -(float)(I1 + 4096 * I2 + 1);
        else             enc = FULL_SENTINEL;
        out[IDX_OFF + nbase + tid] = enc;
    }
}

// ---- K2a: pair rescore. One wave scans 64 rows (coalesced), rescores negatives. ----
__global__ __launch_bounds__(256) void vq_resolve_pair(const float* __restrict__ z,
                                                       const float* __restrict__ e,
                                                       float* __restrict__ out) {
    const int wave = threadIdx.x >> 6, lane = threadIdx.x & 63;
    const int wid = blockIdx.x * 4 + wave;          // 1024 waves total
    const int base = wid * 64;
    float val = out[IDX_OFF + base + lane];
    unsigned long long mask = __ballot(val < 0.0f);
    while (mask) {
        int j = __ffsll((long long)mask) - 1;
        mask &= mask - 1;
        float fv = __shfl(val, j);
        int t = (int)(-fv) - 1;
        const int c1 = t & 4095, c2 = t >> 12;
        const int gidx = base + j;
        const int b = gidx >> 14, m = gidx & (MB - 1);
        const float* zr = z + (size_t)b * DIM * MB + m;
        const float* e1 = e + (size_t)c1 * DIM;
        const float* e2 = e + (size_t)c2 * DIM;
        double A = 0.0, d1 = 0.0, d2 = 0.0, q1 = 0.0, q2 = 0.0;
        #pragma unroll
        for (int jj = 0; jj < 4; ++jj) {
            int d = lane * 4 + jj;
            double zv = (double)zr[(size_t)d * MB];
            double v1 = (double)e1[d], v2 = (double)e2[d];
            A = fma(zv, zv, A);
            d1 = fma(zv, v1, d1); d2 = fma(zv, v2, d2);
            q1 = fma(v1, v1, q1); q2 = fma(v2, v2, q2);
        }
        #pragma unroll
        for (int mm = 1; mm < 64; mm <<= 1) {
            A += __shfl_xor(A, mm); d1 += __shfl_xor(d1, mm); d2 += __shfl_xor(d2, mm);
            q1 += __shfl_xor(q1, mm); q2 += __shfl_xor(q2, mm);
        }
        if (lane == 0) {
            float Af = (float)A;
            float s1 = (Af - (float)(2.0 * d1)) + (float)q1;
            float s2 = (Af - (float)(2.0 * d2)) + (float)q2;
            int idx = (s2 < s1) ? c2 : ((s1 < s2) ? c1 : (c1 < c2 ? c1 : c2));
            out[IDX_OFF + gidx] = (float)idx;
        }
    }
}

// ---- K2b: full-row exact rescan for sentinel rows. Block scans 64 rows. ----
__global__ __launch_bounds__(256) void vq_resolve_full(const float* __restrict__ z,
                                                       const float* __restrict__ e,
                                                       float* __restrict__ out) {
    __shared__ float rv[4];
    __shared__ int ri[4];
    const int tid = threadIdx.x;
    const int wave = tid >> 6, lane = tid & 63;
    const int base = blockIdx.x * 64;               // 1024 blocks
    for (int j = 0; j < 64; ++j) {
        float val = out[IDX_OFF + base + j];        // uniform load
        if (val < 16777216.0f) continue;
        const int gidx = base + j;
        const int b = gidx >> 14, m = gidx & (MB - 1);
        const float* zr = z + (size_t)b * DIM * MB + m;
        double A = 0.0;
        for (int d = 0; d < DIM; ++d) {
            double zv = (double)zr[(size_t)d * MB];
            A = fma(zv, zv, A);
        }
        const float Af = (float)A;
        float bsv = FLT_MAX; int bsk = 0;
        for (int kk = 0; kk < 16; ++kk) {
            const int k = kk * 256 + tid;           // ascending per thread
            const float* er = e + (size_t)k * DIM;
            double dot = 0.0, cs = 0.0;
            #pragma unroll 4
            for (int d = 0; d < DIM; ++d) {
                double ev = (double)er[d];
                dot = fma((double)zr[(size_t)d * MB], ev, dot);
                cs = fma(ev, ev, cs);
            }
            float s = (Af - (float)(2.0 * dot)) + (float)cs;
            if (s < bsv) { bsv = s; bsk = k; }
        }
        #pragma unroll
        for (int mm = 1; mm < 64; mm <<= 1) {
            float ov = __shfl_xor(bsv, mm);
            int oi = __shfl_xor(bsk, mm);
            if (ov < bsv || (ov == bsv && oi < bsk)) { bsv = ov; bsk = oi; }
        }
        if (lane == 0) { rv[wave] = bsv; ri[wave] = bsk; }
        __syncthreads();
        if (tid == 0) {
            float bv = rv[0]; int bk = ri[0];
            #pragma unroll
            for (int wv = 1; wv < 4; ++wv) {
                if (rv[wv] < bv || (rv[wv] == bv && ri[wv] < bk)) { bv = rv[wv]; bk = ri[wv]; }
            }
            out[IDX_OFF + gidx] = (float)bk;
        }
        __syncthreads();
    }
}

// ---- K3: z_q scatter + fused loss, reading final indices from out ----
__global__ __launch_bounds__(256) void vq_apply(const float* __restrict__ z,
                                                const float* __restrict__ e,
                                                float* __restrict__ out) {
    __shared__ int lds_fi[64];
    __shared__ double lds_ls[4];
    const int tid = threadIdx.x;
    const int wave = tid >> 6, lane = tid & 63;
    const int nbase = blockIdx.x * 64;
    const int b = nbase / MB;
    const int mbase = nbase % MB;
    if (tid < 64) lds_fi[tid] = (int)out[IDX_OFF + nbase + tid];
    __syncthreads();

    double lsum = 0.0;
    const int mloc = tid & 63;
    const int d0 = tid >> 6;
    const int code = lds_fi[mloc];
    const float* erow = e + (size_t)code * DIM;
    #pragma unroll 4
    for (int d = d0; d < DIM; d += 4) {
        float ev = erow[d];
        size_t off = (size_t)b * (DIM * MB) + (size_t)d * MB + mbase + mloc;
        float zv = z[off];
        out[off] = ev;
        float diff = ev - zv;
        lsum += (double)diff * diff;
    }
    #pragma unroll
    for (int off = 32; off > 0; off >>= 1) lsum += __shfl_down(lsum, off);
    if (lane == 0) lds_ls[wave] = lsum;
    __syncthreads();
    if (tid == 0) {
        double t = lds_ls[0] + lds_ls[1] + lds_ls[2] + lds_ls[3];
        atomicAdd(out + LOSS_OFF, (float)(t * (1.25 / (double)ZELEMS)));
    }
}

extern "C" void kernel_launch(void* const* d_in, const int* in_sizes, int n_in,
                              void* d_out, int out_size, void* d_ws, size_t ws_size,
                              hipStream_t stream) {
    const float* z = (const float*)d_in[0];    // [4,256,16,32,32] fp32
    const float* e = (const float*)d_in[1];    // [4096,256] fp32
    float* out = (float*)d_out;

    hipMemsetAsync(out + LOSS_OFF, 0, sizeof(float), stream);
    vq_fast<<<NTOT / 128, 256, 0, stream>>>(z, e, out);
    vq_resolve_pair<<<NTOT / 256, 256, 0, stream>>>(z, e, out);
    vq_resolve_full<<<NTOT / 64, 256, 0, stream>>>(z, e, out);
    vq_apply<<<NTOT / 64, 256, 0, stream>>>(z, e, out);
}

// Round 9
// 5013.108 us; speedup vs baseline: 13.1866x; 13.1866x over previous
//
#include <hip/hip_runtime.h>
#include <float.h>

#define KC 4096
#define DIM 256
#define MB 16384            // m per batch element (16*32*32)
#define NTOT 65536          // rows
#define ZELEMS 16777216
#define LOSS_OFF 16777216
#define IDX_OFF  16777217
#define TAU 4.5e-5f         // window: > ULP(256)=3.05e-5 + 2*eps + slack
#define FULL_SENTINEL 33554432.0f   // 2^25, exact in f32

// exact merge of two sorted top-3 sets; indices kept for slots 1,2 only.
__device__ __forceinline__ void merge3(float& b1, int& i1, float& b2, int& i2, float& b3,
                                       float c1, int j1, float c2, int j2, float c3) {
    bool aw = (b1 < c1) || (b1 == c1 && i1 < j1);
    float x1 = aw ? b1 : c1; int xi1 = aw ? i1 : j1;
    float x2 = aw ? b2 : c2; int xi2 = aw ? i2 : j2;
    float x3 = aw ? b3 : c3;
    float y1 = aw ? c1 : b1; int yi1 = aw ? j1 : i1;
    float y2 = aw ? c2 : b2;
    bool s2 = (x2 < y1) || (x2 == y1 && xi2 < yi1);
    float o2 = s2 ? x2 : y1; int oi2 = s2 ? xi2 : yi1;
    float o3 = s2 ? fminf(x3, y1) : fminf(x2, y2);
    b1 = x1; i1 = xi1; b2 = o2; i2 = oi2; b3 = o3;
}

// ---- K1: f32 fast pass with EXACT top-3 tracking. Block = 128 rows. ----
// In-band encoding into out[IDX_OFF+row]:
//   b2 >  b1+TAU : plain I1 (0..4095)                  -> final
//   b3 >  b1+TAU : -(I1 + 4096*I2 + 1) (<=2^24 exact)  -> pair rescore
//   else         : 2^25                                -> full rescan
__global__ __launch_bounds__(256) void vq_fast(const float* __restrict__ z,
                                               const float* __restrict__ e,
                                               float* __restrict__ out) {
    __shared__ float lds_ep[DIM][34];
    __shared__ float mb1[4][128], mb2[4][128], mb3[4][128];
    __shared__ int   mi1[4][128], mi2[4][128];

    const int tid = threadIdx.x;
    const int wave = tid >> 6, lane = tid & 63;
    const int l16 = lane & 15, g = lane >> 4;
    const int nbase = blockIdx.x * 128;
    const int b = nbase / MB;
    const int mbase = nbase % MB;
    const float* zb = z + (size_t)b * DIM * MB;
    const int mrow = mbase + 4 * l16;
    const int cw = wave * 8 + g * 2;

    float b1[8], b2[8], b3[8];
    int i1[8], i2[8];
    #pragma unroll
    for (int i = 0; i < 8; ++i) { b1[i] = FLT_MAX; b2[i] = FLT_MAX; b3[i] = FLT_MAX; i1[i] = 0; i2[i] = 0; }

    for (int chunk = 0; chunk < KC / 32; ++chunk) {
        const int cbase = chunk * 32;
        {   // stage 32 codes x 256 d, transposed to [d][code]
            const float4* src = reinterpret_cast<const float4*>(e + (size_t)cbase * DIM);
            #pragma unroll
            for (int i = 0; i < 8; ++i) {
                int f = tid + 256 * i;
                int code = f >> 6;
                int dw = (f & 63) * 4;
                float4 v = src[f];
                lds_ep[dw][code] = v.x; lds_ep[dw + 1][code] = v.y;
                lds_ep[dw + 2][code] = v.z; lds_ep[dw + 3][code] = v.w;
            }
        }
        __syncthreads();

        // |e|^2 (fp64 -> f32) for this lane's 2 codes, coop across 16 lanes
        double cs0 = 0.0, cs1 = 0.0;
        #pragma unroll
        for (int dd = 0; dd < 16; ++dd) {
            float a0 = lds_ep[l16 * 16 + dd][cw];
            float a1 = lds_ep[l16 * 16 + dd][cw + 1];
            cs0 += (double)a0 * a0;
            cs1 += (double)a1 * a1;
        }
        #pragma unroll
        for (int m = 1; m < 16; m <<= 1) { cs0 += __shfl_xor(cs0, m); cs1 += __shfl_xor(cs1, m); }
        const float bf0 = (float)cs0, bf1 = (float)cs1;

        float acc[8][2];
        #pragma unroll
        for (int i = 0; i < 8; ++i) { acc[i][0] = 0.f; acc[i][1] = 0.f; }

        #pragma unroll 4
        for (int d = 0; d < DIM; ++d) {
            const float2 ep = *reinterpret_cast<const float2*>(&lds_ep[d][cw]);
            float4 za = *reinterpret_cast<const float4*>(zb + (size_t)d * MB + mrow);
            float4 zc = *reinterpret_cast<const float4*>(zb + (size_t)d * MB + mrow + 64);
            acc[0][0] = fmaf(za.x, ep.x, acc[0][0]); acc[0][1] = fmaf(za.x, ep.y, acc[0][1]);
            acc[1][0] = fmaf(za.y, ep.x, acc[1][0]); acc[1][1] = fmaf(za.y, ep.y, acc[1][1]);
            acc[2][0] = fmaf(za.z, ep.x, acc[2][0]); acc[2][1] = fmaf(za.z, ep.y, acc[2][1]);
            acc[3][0] = fmaf(za.w, ep.x, acc[3][0]); acc[3][1] = fmaf(za.w, ep.y, acc[3][1]);
            acc[4][0] = fmaf(zc.x, ep.x, acc[4][0]); acc[4][1] = fmaf(zc.x, ep.y, acc[4][1]);
            acc[5][0] = fmaf(zc.y, ep.x, acc[5][0]); acc[5][1] = fmaf(zc.y, ep.y, acc[5][1]);
            acc[6][0] = fmaf(zc.z, ep.x, acc[6][0]); acc[6][1] = fmaf(zc.z, ep.y, acc[6][1]);
            acc[7][0] = fmaf(zc.w, ep.x, acc[7][0]); acc[7][1] = fmaf(zc.w, ep.y, acc[7][1]);
        }

        const int k0 = cbase + cw;
        #pragma unroll
        for (int i = 0; i < 8; ++i) {
            #pragma unroll
            for (int c = 0; c < 2; ++c) {
                float s = fmaf(-2.0f, acc[i][c], c ? bf1 : bf0);
                int k = k0 + c;
                // sorted insert; strict < + ascending k preserves first-index tie rule
                if (s < b1[i])      { b3[i] = b2[i]; b2[i] = b1[i]; i2[i] = i1[i]; b1[i] = s; i1[i] = k; }
                else if (s < b2[i]) { b3[i] = b2[i]; b2[i] = s; i2[i] = k; }
                else if (s < b3[i]) { b3[i] = s; }
            }
        }
        __syncthreads();
    }

    // exact top-3 merge across the 4 g-groups (xor 16, 32)
    #pragma unroll
    for (int off = 16; off < 64; off <<= 1) {
        #pragma unroll
        for (int i = 0; i < 8; ++i) {
            float ob1 = __shfl_xor(b1[i], off), ob2 = __shfl_xor(b2[i], off), ob3 = __shfl_xor(b3[i], off);
            int oi1 = __shfl_xor(i1[i], off), oi2 = __shfl_xor(i2[i], off);
            merge3(b1[i], i1[i], b2[i], i2[i], b3[i], ob1, oi1, ob2, oi2, ob3);
        }
    }
    if (g == 0) {
        #pragma unroll
        for (int i = 0; i < 8; ++i) {
            int r = (i < 4) ? (4 * l16 + i) : (64 + 4 * l16 + (i - 4));
            mb1[wave][r] = b1[i]; mb2[wave][r] = b2[i]; mb3[wave][r] = b3[i];
            mi1[wave][r] = i1[i]; mi2[wave][r] = i2[i];
        }
    }
    __syncthreads();
    if (tid < 128) {
        float B1 = mb1[0][tid], B2 = mb2[0][tid], B3 = mb3[0][tid];
        int I1 = mi1[0][tid], I2 = mi2[0][tid];
        #pragma unroll
        for (int wv = 1; wv < 4; ++wv)
            merge3(B1, I1, B2, I2, B3, mb1[wv][tid], mi1[wv][tid], mb2[wv][tid], mi2[wv][tid], mb3[wv][tid]);
        float enc;
        if (B2 > B1 + TAU)      enc = (float)I1;                      // provably unique
        else if (B3 > B1 + TAU) enc = -(float)(I1 + 4096 * I2 + 1);   // exactly one rival
        else                    enc = FULL_SENTINEL;                  // >=2 rivals
        out[IDX_OFF + nbase + tid] = enc;
    }
}

// ---- K2a: pair rescore (negatives), one wave scans 64 rows. ----
__global__ __launch_bounds__(256) void vq_resolve_pair(const float* __restrict__ z,
                                                       const float* __restrict__ e,
                                                       float* __restrict__ out) {
    const int wave = threadIdx.x >> 6, lane = threadIdx.x & 63;
    const int wid = blockIdx.x * 4 + wave;
    const int base = wid * 64;
    float val = out[IDX_OFF + base + lane];
    unsigned long long mask = __ballot(val < 0.0f);
    while (mask) {
        int j = __ffsll((long long)mask) - 1;
        mask &= mask - 1;
        float fv = __shfl(val, j);
        int t = (int)(-fv) - 1;
        const int c1 = t & 4095, c2 = t >> 12;
        const int gidx = base + j;
        const int b = gidx >> 14, m = gidx & (MB - 1);
        const float* zr = z + (size_t)b * DIM * MB + m;
        const float* e1 = e + (size_t)c1 * DIM;
        const float* e2 = e + (size_t)c2 * DIM;
        double A = 0.0, d1 = 0.0, d2 = 0.0, q1 = 0.0, q2 = 0.0;
        #pragma unroll
        for (int jj = 0; jj < 4; ++jj) {
            int d = lane * 4 + jj;
            double zv = (double)zr[(size_t)d * MB];
            double v1 = (double)e1[d], v2 = (double)e2[d];
            A = fma(zv, zv, A);
            d1 = fma(zv, v1, d1); d2 = fma(zv, v2, d2);
            q1 = fma(v1, v1, q1); q2 = fma(v2, v2, q2);
        }
        #pragma unroll
        for (int mm = 1; mm < 64; mm <<= 1) {
            A += __shfl_xor(A, mm); d1 += __shfl_xor(d1, mm); d2 += __shfl_xor(d2, mm);
            q1 += __shfl_xor(q1, mm); q2 += __shfl_xor(q2, mm);
        }
        if (lane == 0) {
            float Af = (float)A;
            float s1 = (Af - (float)(2.0 * d1)) + (float)q1;
            float s2 = (Af - (float)(2.0 * d2)) + (float)q2;
            int idx = (s2 < s1) ? c2 : ((s1 < s2) ? c1 : (c1 < c2 ? c1 : c2));
            out[IDX_OFF + gidx] = (float)idx;
        }
    }
}

// ---- K2b: full exact rescan for sentinel rows (fast path: z in LDS, f4 e). ----
__global__ __launch_bounds__(256) void vq_resolve_full(const float* __restrict__ z,
                                                       const float* __restrict__ e,
                                                       float* __restrict__ out) {
    __shared__ float zs[DIM];
    __shared__ float flg[64];
    __shared__ float rv[4];
    __shared__ int ri[4];
    const int tid = threadIdx.x;
    const int wave = tid >> 6, lane = tid & 63;
    const int base = blockIdx.x * 64;
    if (tid < 64) flg[tid] = out[IDX_OFF + base + tid];
    __syncthreads();
    for (int j = 0; j < 64; ++j) {
        if (flg[j] < 16777216.0f) continue;          // pair-enc are negative; finals <4096
        const int gidx = base + j;
        const int b = gidx >> 14, m = gidx & (MB - 1);
        const float* zr = z + (size_t)b * DIM * MB + m;
        if (tid < DIM) zs[tid] = zr[(size_t)tid * MB];
        __syncthreads();
        // A = |z|^2 fp64, lane-parallel per wave (A-rounding argmin-neutral)
        double av = 0.0;
        #pragma unroll
        for (int t2 = 0; t2 < 4; ++t2) {
            double zv = (double)zs[lane * 4 + t2];
            av = fma(zv, zv, av);
        }
        #pragma unroll
        for (int mm = 1; mm < 64; mm <<= 1) av += __shfl_xor(av, mm);
        const float Af = (float)av;

        float bsv = FLT_MAX; int bsk = 0;
        for (int kk = 0; kk < 16; ++kk) {
            const int k = kk * 256 + tid;            // ascending per thread
            const float4* er4 = reinterpret_cast<const float4*>(e + (size_t)k * DIM);
            const float4* zs4 = reinterpret_cast<const float4*>(zs);
            double dot0 = 0.0, dot1 = 0.0, q0 = 0.0, q1 = 0.0;
            #pragma unroll 8
            for (int d4 = 0; d4 < 64; ++d4) {
                float4 ev = er4[d4];
                float4 zv = zs4[d4];
                dot0 = fma((double)zv.x, (double)ev.x, dot0);
                dot1 = fma((double)zv.y, (double)ev.y, dot1);
                dot0 = fma((double)zv.z, (double)ev.z, dot0);
                dot1 = fma((double)zv.w, (double)ev.w, dot1);
                q0 = fma((double)ev.x, (double)ev.x, q0);
                q1 = fma((double)ev.y, (double)ev.y, q1);
                q0 = fma((double)ev.z, (double)ev.z, q0);
                q1 = fma((double)ev.w, (double)ev.w, q1);
            }
            float s = (Af - (float)(2.0 * (dot0 + dot1))) + (float)(q0 + q1);
            if (s < bsv) { bsv = s; bsk = k; }
        }
        #pragma unroll
        for (int mm = 1; mm < 64; mm <<= 1) {
            float ov = __shfl_xor(bsv, mm);
            int oi = __shfl_xor(bsk, mm);
            if (ov < bsv || (ov == bsv && oi < bsk)) { bsv = ov; bsk = oi; }
        }
        if (lane == 0) { rv[wave] = bsv; ri[wave] = bsk; }
        __syncthreads();
        if (tid == 0) {
            float bv = rv[0]; int bk = ri[0];
            #pragma unroll
            for (int wv = 1; wv < 4; ++wv) {
                if (rv[wv] < bv || (rv[wv] == bv && ri[wv] < bk)) { bv = rv[wv]; bk = ri[wv]; }
            }
            out[IDX_OFF + gidx] = (float)bk;
        }
        __syncthreads();
    }
}

// ---- K3: z_q scatter + fused loss, reading final indices from out ----
__global__ __launch_bounds__(256) void vq_apply(const float* __restrict__ z,
                                                const float* __restrict__ e,
                                                float* __restrict__ out) {
    __shared__ int lds_fi[64];
    __shared__ double lds_ls[4];
    const int tid = threadIdx.x;
    const int wave = tid >> 6, lane = tid & 63;
    const int nbase = blockIdx.x * 64;
    const int b = nbase / MB;
    const int mbase = nbase % MB;
    if (tid < 64) lds_fi[tid] = (int)out[IDX_OFF + nbase + tid];
    __syncthreads();

    double lsum = 0.0;
    const int mloc = tid & 63;
    const int d0 = tid >> 6;
    const int code = lds_fi[mloc];
    const float* erow = e + (size_t)code * DIM;
    #pragma unroll 4
    for (int d = d0; d < DIM; d += 4) {
        float ev = erow[d];
        size_t off = (size_t)b * (DIM * MB) + (size_t)d * MB + mbase + mloc;
        float zv = z[off];
        out[off] = ev;
        float diff = ev - zv;
        lsum += (double)diff * diff;
    }
    #pragma unroll
    for (int off = 32; off > 0; off >>= 1) lsum += __shfl_down(lsum, off);
    if (lane == 0) lds_ls[wave] = lsum;
    __syncthreads();
    if (tid == 0) {
        double t = lds_ls[0] + lds_ls[1] + lds_ls[2] + lds_ls[3];
        atomicAdd(out + LOSS_OFF, (float)(t * (1.25 / (double)ZELEMS)));
    }
}

extern "C" void kernel_launch(void* const* d_in, const int* in_sizes, int n_in,
                              void* d_out, int out_size, void* d_ws, size_t ws_size,
                              hipStream_t stream) {
    const float* z = (const float*)d_in[0];    // [4,256,16,32,32] fp32
    const float* e = (const float*)d_in[1];    // [4096,256] fp32
    float* out = (float*)d_out;

    hipMemsetAsync(out + LOSS_OFF, 0, sizeof(float), stream);
    vq_fast<<<NTOT / 128, 256, 0, stream>>>(z, e, out);
    vq_resolve_pair<<<NTOT / 256, 256, 0, stream>>>(z, e, out);
    vq_resolve_full<<<NTOT / 64, 256, 0, stream>>>(z, e, out);
    vq_apply<<<NTOT / 64, 256, 0, stream>>>(z, e, out);
}

// Round 10
// 1794.126 us; speedup vs baseline: 36.8458x; 2.7942x over previous
//
#include <hip/hip_runtime.h>
#include <float.h>

#define KC 4096
#define DIM 256
#define MB 16384            // m per batch element (16*32*32)
#define NTOT 65536          // rows
#define ZELEMS 16777216
#define LOSS_OFF 16777216
#define IDX_OFF  16777217
// window: ULP(~256)=3.05e-5 (grid step; grid-round is monotone so ref argmin
// is within one step of pre-grid min) + max|e|^2 spread 1.53e-5 + mfma-split
// eps (~2e-6 worst) + BLAS eps + slack
#define TAU 6.5e-5f
#define FULL_SENTINEL 33554432.0f   // 2^25, exact in f32

// scratch layout inside the z_q output region (overwritten by vq_apply later):
#define EH_OFF 0            // 131072 uint4 slots = 2MB (bf16-hi A-fragments)
#define EL_OFF 524288       // float offset; 2MB (bf16-lo A-fragments)
#define BT_OFF 1048576      // f32 |e_k|^2 table, 4096 floats

typedef short s8v __attribute__((ext_vector_type(8)));
typedef float f4v __attribute__((ext_vector_type(4)));

__device__ __forceinline__ ushort f2bf(float f) {   // RNE bf16
    unsigned u = __float_as_uint(f);
    unsigned r = u + 0x7FFFu + ((u >> 16) & 1u);
    return (ushort)(r >> 16);
}
__device__ __forceinline__ float bf2f(ushort h) {
    return __uint_as_float(((unsigned)h) << 16);
}

// exact merge of two sorted top-3 sets; indices kept for slots 1,2 only.
__device__ __forceinline__ void merge3(float& b1, int& i1, float& b2, int& i2, float& b3,
                                       float c1, int j1, float c2, int j2, float c3) {
    bool aw = (b1 < c1) || (b1 == c1 && i1 < j1);
    float x1 = aw ? b1 : c1; int xi1 = aw ? i1 : j1;
    float x2 = aw ? b2 : c2; int xi2 = aw ? i2 : j2;
    float x3 = aw ? b3 : c3;
    float y1 = aw ? c1 : b1; int yi1 = aw ? j1 : i1;
    float y2 = aw ? c2 : b2;
    bool s2 = (x2 < y1) || (x2 == y1 && xi2 < yi1);
    float o2 = s2 ? x2 : y1; int oi2 = s2 ? xi2 : yi1;
    float o3 = s2 ? fminf(x3, y1) : fminf(x2, y2);
    b1 = x1; i1 = xi1; b2 = o2; i2 = oi2; b3 = o3;
}

// ---- P1: |e_k|^2 table (fp64 -> f32), one wave per code ----
__global__ __launch_bounds__(256) void vq_prep_b(const float* __restrict__ e,
                                                 float* __restrict__ out) {
    int k = blockIdx.x * 4 + (threadIdx.x >> 6);
    int lane = threadIdx.x & 63;
    float4 v = reinterpret_cast<const float4*>(e + (size_t)k * DIM)[lane];
    double s = (double)v.x * v.x + (double)v.y * v.y + (double)v.z * v.z + (double)v.w * v.w;
    #pragma unroll
    for (int off = 32; off > 0; off >>= 1) s += __shfl_down(s, off);
    if (lane == 0) out[BT_OFF + k] = (float)s;
}

// ---- P2: e -> bf16-split A-fragment tables.
// Fragment layout (16x16x32 bf16, battle-verified by learn_hip m92/m97 GEMM):
// A row = lane&15 (code%16), k = (lane>>4)*8 + j, k_global = kc*32 + k.
// Slot addr = ((tile*8 + kc)*64 + lane) * 16B, tile = code>>4.
__global__ __launch_bounds__(256) void vq_prep_e(const float* __restrict__ e,
                                                 float* __restrict__ out) {
    int t = blockIdx.x * 256 + threadIdx.x;        // 0..131071
    int code = t >> 5, s8 = t & 31;
    int d0 = s8 * 8;
    const float4* src = reinterpret_cast<const float4*>(e + (size_t)code * DIM + d0);
    float4 v0 = src[0], v1 = src[1];
    float f[8] = {v0.x, v0.y, v0.z, v0.w, v1.x, v1.y, v1.z, v1.w};
    uint4 H, L;
    unsigned* hp = &H.x;
    unsigned* lp = &L.x;
    #pragma unroll
    for (int p = 0; p < 4; ++p) {
        ushort h0 = f2bf(f[2 * p]),     h1 = f2bf(f[2 * p + 1]);
        ushort l0 = f2bf(f[2 * p]     - bf2f(h0));
        ushort l1 = f2bf(f[2 * p + 1] - bf2f(h1));
        hp[p] = (unsigned)h0 | ((unsigned)h1 << 16);
        lp[p] = (unsigned)l0 | ((unsigned)l1 << 16);
    }
    int kc = s8 >> 2, khi = s8 & 3;
    int lane = khi * 16 + (code & 15);
    int slot = ((code >> 4) * 8 + kc) * 64 + lane;
    reinterpret_cast<uint4*>(out + EH_OFF)[slot] = H;
    reinterpret_cast<uint4*>(out + EL_OFF)[slot] = L;
}

// ---- K1: MFMA fast pass. Block = 64 rows (4 waves x 16 rows each). ----
// mfma(A=e_frag, B=z_frag): D col=lane&15 -> z-row (lane-local top3!),
// D reg row=(lane>>4)*4+reg -> code within tile. Codes ascend per lane.
// In-band encoding into out[IDX_OFF+row]:
//   b2 >  b1+TAU : plain I1            -> final
//   b3 >  b1+TAU : -(I1+4096*I2+1)     -> pair rescore
//   else         : 2^25                -> full rescan
__global__ __launch_bounds__(256) void vq_fast(const float* __restrict__ z,
                                               float* __restrict__ out) {
    const int tid = threadIdx.x;
    const int wave = tid >> 6, lane = tid & 63;
    const int khi = lane >> 4;
    const int nbase = blockIdx.x * 64;
    const int b = nbase / MB;
    const int mbase = nbase % MB;
    // this lane's z-row (B-operand col = lane&15 within the wave's 16 rows)
    const float* zlane = z + (size_t)b * DIM * MB + mbase + wave * 16 + (lane & 15);

    // build z B-fragments in registers: zh/zl for 8 K-chunks
    s8v zhf[8], zlf[8];
    #pragma unroll
    for (int kc = 0; kc < 8; ++kc) {
        union { s8v v; ushort u[8]; } H, L;
        #pragma unroll
        for (int j = 0; j < 8; ++j) {
            float zv = zlane[(size_t)(kc * 32 + khi * 8 + j) * MB];
            ushort h = f2bf(zv);
            H.u[j] = h;
            L.u[j] = f2bf(zv - bf2f(h));
        }
        zhf[kc] = H.v; zlf[kc] = L.v;
    }

    const uint4* EH = reinterpret_cast<const uint4*>(out + EH_OFF);
    const uint4* EL = reinterpret_cast<const uint4*>(out + EL_OFF);
    const float* Btab = out + BT_OFF;

    float b1 = FLT_MAX, b2 = FLT_MAX, b3 = FLT_MAX;
    int i1 = 0, i2 = 0;

    for (int tile = 0; tile < KC / 16; ++tile) {
        f4v a0 = {0.f, 0.f, 0.f, 0.f}, a1 = a0, a2 = a0;   // 3 indep chains
        const uint4* ph = EH + (size_t)tile * 8 * 64 + lane;
        const uint4* pl = EL + (size_t)tile * 8 * 64 + lane;
        #pragma unroll
        for (int kc = 0; kc < 8; ++kc) {
            union { uint4 q; s8v v; } ah, al;
            ah.q = ph[kc * 64];
            al.q = pl[kc * 64];
            a0 = __builtin_amdgcn_mfma_f32_16x16x32_bf16(ah.v, zhf[kc], a0, 0, 0, 0);
            a1 = __builtin_amdgcn_mfma_f32_16x16x32_bf16(al.v, zhf[kc], a1, 0, 0, 0);
            a2 = __builtin_amdgcn_mfma_f32_16x16x32_bf16(ah.v, zlf[kc], a2, 0, 0, 0);
        }
        const f4v Bv = *reinterpret_cast<const f4v*>(Btab + tile * 16 + khi * 4);
        #pragma unroll
        for (int i = 0; i < 4; ++i) {
            float g = a0[i] + a1[i] + a2[i];
            float s = fmaf(-2.0f, g, Bv[i]);
            int k = tile * 16 + khi * 4 + i;     // ascending per lane
            if (s < b1)      { b3 = b2; b2 = b1; i2 = i1; b1 = s; i1 = k; }
            else if (s < b2) { b3 = b2; b2 = s; i2 = k; }
            else if (s < b3) { b3 = s; }
        }
    }

    // merge the 4 khi code-groups (lanes sharing lane&15 = same z-row)
    #pragma unroll
    for (int off = 16; off < 64; off <<= 1) {
        float ob1 = __shfl_xor(b1, off), ob2 = __shfl_xor(b2, off), ob3 = __shfl_xor(b3, off);
        int oi1 = __shfl_xor(i1, off), oi2 = __shfl_xor(i2, off);
        merge3(b1, i1, b2, i2, b3, ob1, oi1, ob2, oi2, ob3);
    }
    if (lane < 16) {
        float enc;
        if (b2 > b1 + TAU)      enc = (float)i1;                      // provably unique
        else if (b3 > b1 + TAU) enc = -(float)(i1 + 4096 * i2 + 1);   // one rival
        else                    enc = FULL_SENTINEL;                  // >=2 rivals
        out[IDX_OFF + nbase + wave * 16 + lane] = enc;
    }
}

// ---- K2a: pair rescore (negatives), one wave scans 64 rows. ----
__global__ __launch_bounds__(256) void vq_resolve_pair(const float* __restrict__ z,
                                                       const float* __restrict__ e,
                                                       float* __restrict__ out) {
    const int wave = threadIdx.x >> 6, lane = threadIdx.x & 63;
    const int wid = blockIdx.x * 4 + wave;
    const int base = wid * 64;
    float val = out[IDX_OFF + base + lane];
    unsigned long long mask = __ballot(val < 0.0f);
    while (mask) {
        int j = __ffsll((long long)mask) - 1;
        mask &= mask - 1;
        float fv = __shfl(val, j);
        int t = (int)(-fv) - 1;
        const int c1 = t & 4095, c2 = t >> 12;
        const int gidx = base + j;
        const int b = gidx >> 14, m = gidx & (MB - 1);
        const float* zr = z + (size_t)b * DIM * MB + m;
        const float* e1 = e + (size_t)c1 * DIM;
        const float* e2 = e + (size_t)c2 * DIM;
        double A = 0.0, d1 = 0.0, d2 = 0.0, q1 = 0.0, q2 = 0.0;
        #pragma unroll
        for (int jj = 0; jj < 4; ++jj) {
            int d = lane * 4 + jj;
            double zv = (double)zr[(size_t)d * MB];
            double v1 = (double)e1[d], v2 = (double)e2[d];
            A = fma(zv, zv, A);
            d1 = fma(zv, v1, d1); d2 = fma(zv, v2, d2);
            q1 = fma(v1, v1, q1); q2 = fma(v2, v2, q2);
        }
        #pragma unroll
        for (int mm = 1; mm < 64; mm <<= 1) {
            A += __shfl_xor(A, mm); d1 += __shfl_xor(d1, mm); d2 += __shfl_xor(d2, mm);
            q1 += __shfl_xor(q1, mm); q2 += __shfl_xor(q2, mm);
        }
        if (lane == 0) {
            float Af = (float)A;
            float s1 = (Af - (float)(2.0 * d1)) + (float)q1;
            float s2 = (Af - (float)(2.0 * d2)) + (float)q2;
            int idx = (s2 < s1) ? c2 : ((s1 < s2) ? c1 : (c1 < c2 ? c1 : c2));
            out[IDX_OFF + gidx] = (float)idx;
        }
    }
}

// ---- K2b: full exact rescan for sentinel rows (z staged in LDS). ----
__global__ __launch_bounds__(256) void vq_resolve_full(const float* __restrict__ z,
                                                       const float* __restrict__ e,
                                                       float* __restrict__ out) {
    __shared__ float zs[DIM];
    __shared__ float flg[64];
    __shared__ float rv[4];
    __shared__ int ri[4];
    const int tid = threadIdx.x;
    const int wave = tid >> 6, lane = tid & 63;
    const int base = blockIdx.x * 64;
    if (tid < 64) flg[tid] = out[IDX_OFF + base + tid];
    __syncthreads();
    for (int j = 0; j < 64; ++j) {
        if (flg[j] < 16777216.0f) continue;
        const int gidx = base + j;
        const int b = gidx >> 14, m = gidx & (MB - 1);
        const float* zr = z + (size_t)b * DIM * MB + m;
        if (tid < DIM) zs[tid] = zr[(size_t)tid * MB];
        __syncthreads();
        double av = 0.0;
        #pragma unroll
        for (int t2 = 0; t2 < 4; ++t2) {
            double zv = (double)zs[lane * 4 + t2];
            av = fma(zv, zv, av);
        }
        #pragma unroll
        for (int mm = 1; mm < 64; mm <<= 1) av += __shfl_xor(av, mm);
        const float Af = (float)av;

        float bsv = FLT_MAX; int bsk = 0;
        for (int kk = 0; kk < 16; ++kk) {
            const int k = kk * 256 + tid;
            const float4* er4 = reinterpret_cast<const float4*>(e + (size_t)k * DIM);
            const float4* zs4 = reinterpret_cast<const float4*>(zs);
            double dot0 = 0.0, dot1 = 0.0, q0 = 0.0, q1 = 0.0;
            #pragma unroll 8
            for (int d4 = 0; d4 < 64; ++d4) {
                float4 ev = er4[d4];
                float4 zv = zs4[d4];
                dot0 = fma((double)zv.x, (double)ev.x, dot0);
                dot1 = fma((double)zv.y, (double)ev.y, dot1);
                dot0 = fma((double)zv.z, (double)ev.z, dot0);
                dot1 = fma((double)zv.w, (double)ev.w, dot1);
                q0 = fma((double)ev.x, (double)ev.x, q0);
                q1 = fma((double)ev.y, (double)ev.y, q1);
                q0 = fma((double)ev.z, (double)ev.z, q0);
                q1 = fma((double)ev.w, (double)ev.w, q1);
            }
            float s = (Af - (float)(2.0 * (dot0 + dot1))) + (float)(q0 + q1);
            if (s < bsv) { bsv = s; bsk = k; }
        }
        #pragma unroll
        for (int mm = 1; mm < 64; mm <<= 1) {
            float ov = __shfl_xor(bsv, mm);
            int oi = __shfl_xor(bsk, mm);
            if (ov < bsv || (ov == bsv && oi < bsk)) { bsv = ov; bsk = oi; }
        }
        if (lane == 0) { rv[wave] = bsv; ri[wave] = bsk; }
        __syncthreads();
        if (tid == 0) {
            float bv = rv[0]; int bk = ri[0];
            #pragma unroll
            for (int wv = 1; wv < 4; ++wv) {
                if (rv[wv] < bv || (rv[wv] == bv && ri[wv] < bk)) { bv = rv[wv]; bk = ri[wv]; }
            }
            out[IDX_OFF + gidx] = (float)bk;
        }
        __syncthreads();
    }
}

// ---- K3: z_q scatter + fused loss (overwrites the scratch region too) ----
__global__ __launch_bounds__(256) void vq_apply(const float* __restrict__ z,
                                                const float* __restrict__ e,
                                                float* __restrict__ out) {
    __shared__ int lds_fi[64];
    __shared__ double lds_ls[4];
    const int tid = threadIdx.x;
    const int wave = tid >> 6, lane = tid & 63;
    const int nbase = blockIdx.x * 64;
    const int b = nbase / MB;
    const int mbase = nbase % MB;
    if (tid < 64) lds_fi[tid] = (int)out[IDX_OFF + nbase + tid];
    __syncthreads();

    double lsum = 0.0;
    const int mloc = tid & 63;
    const int d0 = tid >> 6;
    const int code = lds_fi[mloc];
    const float* erow = e + (size_t)code * DIM;
    #pragma unroll 4
    for (int d = d0; d < DIM; d += 4) {
        float ev = erow[d];
        size_t off = (size_t)b * (DIM * MB) + (size_t)d * MB + mbase + mloc;
        float zv = z[off];
        out[off] = ev;
        float diff = ev - zv;
        lsum += (double)diff * diff;
    }
    #pragma unroll
    for (int off = 32; off > 0; off >>= 1) lsum += __shfl_down(lsum, off);
    if (lane == 0) lds_ls[wave] = lsum;
    __syncthreads();
    if (tid == 0) {
        double t = lds_ls[0] + lds_ls[1] + lds_ls[2] + lds_ls[3];
        atomicAdd(out + LOSS_OFF, (float)(t * (1.25 / (double)ZELEMS)));
    }
}

extern "C" void kernel_launch(void* const* d_in, const int* in_sizes, int n_in,
                              void* d_out, int out_size, void* d_ws, size_t ws_size,
                              hipStream_t stream) {
    const float* z = (const float*)d_in[0];    // [4,256,16,32,32] fp32
    const float* e = (const float*)d_in[1];    // [4096,256] fp32
    float* out = (float*)d_out;

    hipMemsetAsync(out + LOSS_OFF, 0, sizeof(float), stream);
    vq_prep_b<<<KC / 4, 256, 0, stream>>>(e, out);
    vq_prep_e<<<512, 256, 0, stream>>>(e, out);
    vq_fast<<<NTOT / 64, 256, 0, stream>>>(z, out);
    vq_resolve_pair<<<NTOT / 256, 256, 0, stream>>>(z, e, out);
    vq_resolve_full<<<NTOT / 64, 256, 0, stream>>>(z, e, out);
    vq_apply<<<NTOT / 64, 256, 0, stream>>>(z, e, out);
}

// Round 11
// 1392.357 us; speedup vs baseline: 47.4778x; 1.2886x over previous
//
#include <hip/hip_runtime.h>
#include <float.h>

#define KC 4096
#define DIM 256
#define MB 16384            // m per batch element (16*32*32)
#define NTOT 65536          // rows
#define ZELEMS 16777216
#define LOSS_OFF 16777216
#define IDX_OFF  16777217
// TAU: grid step ULP(256)=3.05e-5 + ref-B spread 1.53e-5 + 2*eps_fp16
// (eps <= 2^-10 * sqrt(A*B) <= 4.3e-5 worst-row, Cauchy-Schwarz) + slack
#define TAU 1.5e-4f
#define FULL_SENTINEL 33554432.0f   // 2^25, exact in f32

// scratch inside z_q output region (overwritten by vq_apply at the end):
// fp16 e' table (e*4096): 131072 slots x 16B = 2MB = floats [0, 524288)
#define BT_OFF 524288       // f32 |e_k|^2 table, 4096 floats

typedef _Float16 h8 __attribute__((ext_vector_type(8)));
typedef float f4v __attribute__((ext_vector_type(4)));

// exact merge of two sorted top-3 sets; indices kept for slots 1,2 only.
__device__ __forceinline__ void merge3(float& b1, int& i1, float& b2, int& i2, float& b3,
                                       float c1, int j1, float c2, int j2, float c3) {
    bool aw = (b1 < c1) || (b1 == c1 && i1 < j1);
    float x1 = aw ? b1 : c1; int xi1 = aw ? i1 : j1;
    float x2 = aw ? b2 : c2; int xi2 = aw ? i2 : j2;
    float x3 = aw ? b3 : c3;
    float y1 = aw ? c1 : b1; int yi1 = aw ? j1 : i1;
    float y2 = aw ? c2 : b2;
    bool s2 = (x2 < y1) || (x2 == y1 && xi2 < yi1);
    float o2 = s2 ? x2 : y1; int oi2 = s2 ? xi2 : yi1;
    float o3 = s2 ? fminf(x3, y1) : fminf(x2, y2);
    b1 = x1; i1 = xi1; b2 = o2; i2 = oi2; b3 = o3;
}

__device__ __forceinline__ float enc3(float B1, float B2, float B3, int I1, int I2) {
    if (B2 > B1 + TAU) return (float)I1;                     // provably unique
    if (B3 > B1 + TAU) return -(float)(I1 + 4096 * I2 + 1);  // exactly one rival (<=2^24)
    return FULL_SENTINEL;                                    // >=2 rivals
}

// ---- P1: |e_k|^2 table (fp64 -> f32), one wave per code ----
__global__ __launch_bounds__(256) void vq_prep_b(const float* __restrict__ e,
                                                 float* __restrict__ out) {
    int k = blockIdx.x * 4 + (threadIdx.x >> 6);
    int lane = threadIdx.x & 63;
    float4 v = reinterpret_cast<const float4*>(e + (size_t)k * DIM)[lane];
    double s = (double)v.x * v.x + (double)v.y * v.y + (double)v.z * v.z + (double)v.w * v.w;
    #pragma unroll
    for (int off = 32; off > 0; off >>= 1) s += __shfl_down(s, off);
    if (lane == 0) out[BT_OFF + k] = (float)s;
}

// ---- P2: e' = e*4096 -> fp16 A-fragment table (R10-verified geometry) ----
// A row = lane&15 (code%16), k = (lane>>4)*8 + j, k_global = kc*32 + k.
// Slot = ((tile*8 + kc)*64 + lane), tile = code>>4, 16B per slot.
__global__ __launch_bounds__(256) void vq_prep_e(const float* __restrict__ e,
                                                 float* __restrict__ out) {
    int t = blockIdx.x * 256 + threadIdx.x;        // 0..131071
    int code = t >> 5, s8 = t & 31;
    const float4* src = reinterpret_cast<const float4*>(e + (size_t)code * DIM + s8 * 8);
    float4 v0 = src[0], v1 = src[1];
    float f[8] = {v0.x, v0.y, v0.z, v0.w, v1.x, v1.y, v1.z, v1.w};
    union { uint4 q; _Float16 h[8]; } P;
    #pragma unroll
    for (int p = 0; p < 8; ++p) P.h[p] = (_Float16)(f[p] * 4096.0f);  // exact scale, RNE cvt
    int kc = s8 >> 2, khi = s8 & 3;
    int lane = khi * 16 + (code & 15);
    int slot = ((code >> 4) * 8 + kc) * 64 + lane;
    reinterpret_cast<uint4*>(out)[slot] = P.q;
}

// ---- K1: fp16 MFMA fast pass. Block = 128 rows (4 waves x 32 rows). ----
// Per tile (16 codes): stage 8KB A-frags to LDS (shared by 4 waves),
// each wave: 8 x {ds_read_b128 ; 2 MFMA (row-sets)}. Next tile's frags
// prefetched to regs during compute (T14 split).
__global__ __launch_bounds__(256) void vq_fast(const float* __restrict__ z,
                                               float* __restrict__ out) {
    __shared__ uint4 etile[512];                   // 8KB, one tile of A-frags
    const int tid = threadIdx.x;
    const int wave = tid >> 6, lane = tid & 63;
    const int khi = lane >> 4, l16 = lane & 15;
    const int nbase = blockIdx.x * 128;
    const int b = nbase / MB;
    const int mbase = nbase % MB;
    const float* zb = z + (size_t)b * DIM * MB + mbase + wave * 32 + l16;

    // z B-fragments (fp16), 2 row-sets x 8 kc; set s row = wave*32 + s*16 + l16
    h8 zf0[8], zf1[8];
    #pragma unroll
    for (int kc = 0; kc < 8; ++kc) {
        h8 va, vb;
        #pragma unroll
        for (int j = 0; j < 8; ++j) {
            size_t off = (size_t)(kc * 32 + khi * 8 + j) * MB;
            va[j] = (_Float16)zb[off];
            vb[j] = (_Float16)zb[off + 16];
        }
        zf0[kc] = va; zf1[kc] = vb;
    }

    const uint4* ET = reinterpret_cast<const uint4*>(out);
    const float* Btab = out + BT_OFF;

    float b10 = FLT_MAX, b20 = FLT_MAX, b30 = FLT_MAX;
    float b11 = FLT_MAX, b21 = FLT_MAX, b31 = FLT_MAX;
    int i10 = 0, i20 = 0, i11 = 0, i21 = 0;

    uint4 r0 = ET[tid], r1 = ET[tid + 256];        // preload tile 0

    for (int tile = 0; tile < KC / 16; ++tile) {
        etile[tid] = r0; etile[tid + 256] = r1;
        __syncthreads();
        if (tile < KC / 16 - 1) {                  // prefetch next tile to regs
            r0 = ET[(tile + 1) * 512 + tid];
            r1 = ET[(tile + 1) * 512 + tid + 256];
        }

        f4v a0 = {0.f, 0.f, 0.f, 0.f}, a1 = a0;
        #pragma unroll
        for (int kc = 0; kc < 8; ++kc) {
            union { uint4 q; h8 v; } af;
            af.q = etile[kc * 64 + lane];          // ds_read_b128, conflict-free
            a0 = __builtin_amdgcn_mfma_f32_16x16x32_f16(af.v, zf0[kc], a0, 0, 0, 0);
            a1 = __builtin_amdgcn_mfma_f32_16x16x32_f16(af.v, zf1[kc], a1, 0, 0, 0);
        }

        const f4v Bv = *reinterpret_cast<const f4v*>(Btab + tile * 16 + khi * 4);
        #pragma unroll
        for (int i = 0; i < 4; ++i) {
            int k = tile * 16 + khi * 4 + i;       // ascending per lane
            // s = B - 2G; G' = 4096*G from scaled table -> coeff -1/2048 (exact)
            float s0 = fmaf(-4.8828125e-4f, a0[i], Bv[i]);
            float s1 = fmaf(-4.8828125e-4f, a1[i], Bv[i]);
            if (s0 < b10)      { b30 = b20; b20 = b10; i20 = i10; b10 = s0; i10 = k; }
            else if (s0 < b20) { b30 = b20; b20 = s0; i20 = k; }
            else if (s0 < b30) { b30 = s0; }
            if (s1 < b11)      { b31 = b21; b21 = b11; i21 = i11; b11 = s1; i11 = k; }
            else if (s1 < b21) { b31 = b21; b21 = s1; i21 = k; }
            else if (s1 < b31) { b31 = s1; }
        }
        __syncthreads();
    }

    // merge the 4 khi code-groups (lanes sharing l16 = same z-row)
    #pragma unroll
    for (int off = 16; off < 64; off <<= 1) {
        merge3(b10, i10, b20, i20, b30,
               __shfl_xor(b10, off), __shfl_xor(i10, off),
               __shfl_xor(b20, off), __shfl_xor(i20, off), __shfl_xor(b30, off));
        merge3(b11, i11, b21, i21, b31,
               __shfl_xor(b11, off), __shfl_xor(i11, off),
               __shfl_xor(b21, off), __shfl_xor(i21, off), __shfl_xor(b31, off));
    }
    if (lane < 16) {
        out[IDX_OFF + nbase + wave * 32 + lane]      = enc3(b10, b20, b30, i10, i20);
        out[IDX_OFF + nbase + wave * 32 + 16 + lane] = enc3(b11, b21, b31, i11, i21);
    }
}

// ---- K2a: pair rescore (negatives), one wave scans 64 rows. ----
__global__ __launch_bounds__(256) void vq_resolve_pair(const float* __restrict__ z,
                                                       const float* __restrict__ e,
                                                       float* __restrict__ out) {
    const int wave = threadIdx.x >> 6, lane = threadIdx.x & 63;
    const int wid = blockIdx.x * 4 + wave;
    const int base = wid * 64;
    float val = out[IDX_OFF + base + lane];
    unsigned long long mask = __ballot(val < 0.0f);
    while (mask) {
        int j = __ffsll((long long)mask) - 1;
        mask &= mask - 1;
        float fv = __shfl(val, j);
        int t = (int)(-fv) - 1;
        const int c1 = t & 4095, c2 = t >> 12;
        const int gidx = base + j;
        const int b = gidx >> 14, m = gidx & (MB - 1);
        const float* zr = z + (size_t)b * DIM * MB + m;
        const float* e1 = e + (size_t)c1 * DIM;
        const float* e2 = e + (size_t)c2 * DIM;
        double A = 0.0, d1 = 0.0, d2 = 0.0, q1 = 0.0, q2 = 0.0;
        #pragma unroll
        for (int jj = 0; jj < 4; ++jj) {
            int d = lane * 4 + jj;
            double zv = (double)zr[(size_t)d * MB];
            double v1 = (double)e1[d], v2 = (double)e2[d];
            A = fma(zv, zv, A);
            d1 = fma(zv, v1, d1); d2 = fma(zv, v2, d2);
            q1 = fma(v1, v1, q1); q2 = fma(v2, v2, q2);
        }
        #pragma unroll
        for (int mm = 1; mm < 64; mm <<= 1) {
            A += __shfl_xor(A, mm); d1 += __shfl_xor(d1, mm); d2 += __shfl_xor(d2, mm);
            q1 += __shfl_xor(q1, mm); q2 += __shfl_xor(q2, mm);
        }
        if (lane == 0) {
            float Af = (float)A;
            float s1 = (Af - (float)(2.0 * d1)) + (float)q1;
            float s2 = (Af - (float)(2.0 * d2)) + (float)q2;
            int idx = (s2 < s1) ? c2 : ((s1 < s2) ? c1 : (c1 < c2 ? c1 : c2));
            out[IDX_OFF + gidx] = (float)idx;
        }
    }
}

// ---- K2b: full exact rescan for sentinel rows (z staged in LDS). ----
__global__ __launch_bounds__(256) void vq_resolve_full(const float* __restrict__ z,
                                                       const float* __restrict__ e,
                                                       float* __restrict__ out) {
    __shared__ float zs[DIM];
    __shared__ float flg[64];
    __shared__ float rv[4];
    __shared__ int ri[4];
    const int tid = threadIdx.x;
    const int wave = tid >> 6, lane = tid & 63;
    const int base = blockIdx.x * 64;
    if (tid < 64) flg[tid] = out[IDX_OFF + base + tid];
    __syncthreads();
    for (int j = 0; j < 64; ++j) {
        if (flg[j] < 16777216.0f) continue;
        const int gidx = base + j;
        const int b = gidx >> 14, m = gidx & (MB - 1);
        const float* zr = z + (size_t)b * DIM * MB + m;
        if (tid < DIM) zs[tid] = zr[(size_t)tid * MB];
        __syncthreads();
        double av = 0.0;
        #pragma unroll
        for (int t2 = 0; t2 < 4; ++t2) {
            double zv = (double)zs[lane * 4 + t2];
            av = fma(zv, zv, av);
        }
        #pragma unroll
        for (int mm = 1; mm < 64; mm <<= 1) av += __shfl_xor(av, mm);
        const float Af = (float)av;

        float bsv = FLT_MAX; int bsk = 0;
        for (int kk = 0; kk < 16; ++kk) {
            const int k = kk * 256 + tid;
            const float4* er4 = reinterpret_cast<const float4*>(e + (size_t)k * DIM);
            const float4* zs4 = reinterpret_cast<const float4*>(zs);
            double dot0 = 0.0, dot1 = 0.0, q0 = 0.0, q1 = 0.0;
            #pragma unroll 8
            for (int d4 = 0; d4 < 64; ++d4) {
                float4 ev = er4[d4];
                float4 zv = zs4[d4];
                dot0 = fma((double)zv.x, (double)ev.x, dot0);
                dot1 = fma((double)zv.y, (double)ev.y, dot1);
                dot0 = fma((double)zv.z, (double)ev.z, dot0);
                dot1 = fma((double)zv.w, (double)ev.w, dot1);
                q0 = fma((double)ev.x, (double)ev.x, q0);
                q1 = fma((double)ev.y, (double)ev.y, q1);
                q0 = fma((double)ev.z, (double)ev.z, q0);
                q1 = fma((double)ev.w, (double)ev.w, q1);
            }
            float s = (Af - (float)(2.0 * (dot0 + dot1))) + (float)(q0 + q1);
            if (s < bsv) { bsv = s; bsk = k; }
        }
        #pragma unroll
        for (int mm = 1; mm < 64; mm <<= 1) {
            float ov = __shfl_xor(bsv, mm);
            int oi = __shfl_xor(bsk, mm);
            if (ov < bsv || (ov == bsv && oi < bsk)) { bsv = ov; bsk = oi; }
        }
        if (lane == 0) { rv[wave] = bsv; ri[wave] = bsk; }
        __syncthreads();
        if (tid == 0) {
            float bv = rv[0]; int bk = ri[0];
            #pragma unroll
            for (int wv = 1; wv < 4; ++wv) {
                if (rv[wv] < bv || (rv[wv] == bv && ri[wv] < bk)) { bv = rv[wv]; bk = ri[wv]; }
            }
            out[IDX_OFF + gidx] = (float)bk;
        }
        __syncthreads();
    }
}

// ---- K3: z_q scatter + fused loss; e-rows staged in LDS (coalesced) ----
__global__ __launch_bounds__(256) void vq_apply(const float* __restrict__ z,
                                                const float* __restrict__ e,
                                                float* __restrict__ out) {
    __shared__ int lds_fi[64];
    __shared__ float lds_e[64][260];   // 260: 16B-aligned rows, conflict-light reads
    __shared__ double lds_ls[4];
    const int tid = threadIdx.x;
    const int wave = tid >> 6, lane = tid & 63;
    const int nbase = blockIdx.x * 64;
    const int b = nbase / MB;
    const int mbase = nbase % MB;
    if (tid < 64) lds_fi[tid] = (int)out[IDX_OFF + nbase + tid];
    __syncthreads();
    // stage the 64 selected e-rows, coalesced float4
    for (int r = wave; r < 64; r += 4) {
        int code = lds_fi[r];
        float4 v = reinterpret_cast<const float4*>(e + (size_t)code * DIM)[lane];
        *reinterpret_cast<float4*>(&lds_e[r][lane * 4]) = v;
    }
    __syncthreads();

    double lsum = 0.0;
    const int mloc = tid & 63;
    const int d0 = tid >> 6;
    #pragma unroll 4
    for (int d = d0; d < DIM; d += 4) {
        float ev = lds_e[mloc][d];
        size_t off = (size_t)b * (DIM * MB) + (size_t)d * MB + mbase + mloc;
        float zv = z[off];
        out[off] = ev;
        float diff = ev - zv;
        lsum += (double)diff * diff;
    }
    #pragma unroll
    for (int off = 32; off > 0; off >>= 1) lsum += __shfl_down(lsum, off);
    if (lane == 0) lds_ls[wave] = lsum;
    __syncthreads();
    if (tid == 0) {
        double t = lds_ls[0] + lds_ls[1] + lds_ls[2] + lds_ls[3];
        atomicAdd(out + LOSS_OFF, (float)(t * (1.25 / (double)ZELEMS)));
    }
}

extern "C" void kernel_launch(void* const* d_in, const int* in_sizes, int n_in,
                              void* d_out, int out_size, void* d_ws, size_t ws_size,
                              hipStream_t stream) {
    const float* z = (const float*)d_in[0];    // [4,256,16,32,32] fp32
    const float* e = (const float*)d_in[1];    // [4096,256] fp32
    float* out = (float*)d_out;

    hipMemsetAsync(out + LOSS_OFF, 0, sizeof(float), stream);
    vq_prep_b<<<KC / 4, 256, 0, stream>>>(e, out);
    vq_prep_e<<<512, 256, 0, stream>>>(e, out);
    vq_fast<<<NTOT / 128, 256, 0, stream>>>(z, out);
    vq_resolve_pair<<<NTOT / 256, 256, 0, stream>>>(z, e, out);
    vq_resolve_full<<<NTOT / 64, 256, 0, stream>>>(z, e, out);
    vq_apply<<<NTOT / 64, 256, 0, stream>>>(z, e, out);
}

// Round 12
// 535.475 us; speedup vs baseline: 123.4530x; 2.6002x over previous
//
#include <hip/hip_runtime.h>
#include <float.h>

#define KC 4096
#define DIM 256
#define MB 16384            // m per batch element (16*32*32)
#define NTOT 65536          // rows
#define ZELEMS 16777216
#define LOSS_OFF 16777216
#define IDX_OFF  16777217
// TAU: 2*(grid ULP(256)=3.05e-5) + 2*fp16-chain score err (<=4.7e-5 worst) + slack.
// Validated empirically at 1.5e-4 in R11 (0 misses across 65536 rows).
#define TAU 1.5e-4f

// scratch inside z_q output region (fully overwritten by vq_apply at the end):
// [0, 524288)       fp16 e' A-fragment table (2MB)
#define BT_OFF   524288     // f32 |e_k|^2 table, 4096 floats
#define CNT_OFF  528400     // 2 uints (cand count, full count), 8B-aligned
#define CAND_OFF 532480     // uint4 entries (16B each), cap 65536 -> 1MB
#define FULL_OFF 800000     // uint entries, cap 65536

typedef _Float16 h8 __attribute__((ext_vector_type(8)));
typedef float f4v __attribute__((ext_vector_type(4)));

__device__ __forceinline__ bool lexlt(float av, int ai, float bv, int bi) {
    return (av < bv) || (av == bv && ai < bi);
}

// ---- P1: |e_k|^2 table (fp64 -> f32), one wave per code ----
__global__ __launch_bounds__(256) void vq_prep_b(const float* __restrict__ e,
                                                 float* __restrict__ out) {
    int k = blockIdx.x * 4 + (threadIdx.x >> 6);
    int lane = threadIdx.x & 63;
    float4 v = reinterpret_cast<const float4*>(e + (size_t)k * DIM)[lane];
    double s = (double)v.x * v.x + (double)v.y * v.y + (double)v.z * v.z + (double)v.w * v.w;
    #pragma unroll
    for (int off = 32; off > 0; off >>= 1) s += __shfl_down(s, off);
    if (lane == 0) out[BT_OFF + k] = (float)s;
}

// ---- P2: e' = e*4096 -> fp16 A-fragment table (R10/R11-verified geometry) ----
__global__ __launch_bounds__(256) void vq_prep_e(const float* __restrict__ e,
                                                 float* __restrict__ out) {
    int t = blockIdx.x * 256 + threadIdx.x;        // 0..131071
    int code = t >> 5, s8 = t & 31;
    const float4* src = reinterpret_cast<const float4*>(e + (size_t)code * DIM + s8 * 8);
    float4 v0 = src[0], v1 = src[1];
    float f[8] = {v0.x, v0.y, v0.z, v0.w, v1.x, v1.y, v1.z, v1.w};
    union { uint4 q; _Float16 h[8]; } P;
    #pragma unroll
    for (int p = 0; p < 8; ++p) P.h[p] = (_Float16)(f[p] * 4096.0f);
    int kc = s8 >> 2, khi = s8 & 3;
    int lane = khi * 16 + (code & 15);
    int slot = ((code >> 4) * 8 + kc) * 64 + lane;
    reinterpret_cast<uint4*>(out)[slot] = P.q;
}

// depth-5 sorted insert (indices through slot 4); strict < keeps first-index rule
#define INS5(s, k, B1, I1, B2, I2, B3, I3, B4, I4, B5)                          \
    if (s < B5) {                                                               \
        if (s < B3) {                                                           \
            if (s < B2) {                                                       \
                if (s < B1) { B5=B4; B4=B3; I4=I3; B3=B2; I3=I2; B2=B1; I2=I1; B1=s; I1=k; } \
                else        { B5=B4; B4=B3; I4=I3; B3=B2; I3=I2; B2=s; I2=k; }  \
            } else          { B5=B4; B4=B3; I4=I3; B3=s; I3=k; }                \
        } else {                                                                \
            if (s < B4)     { B5=B4; B4=s; I4=k; }                              \
            else            { B5=s; }                                           \
        }                                                                       \
    }

// one pop step of the sorted-5 merge (a-list by ref, b-list local copies)
#define POPSTEP(rv, riv)                                                        \
    {                                                                           \
        bool t = lexlt(a1, ai1, c1, ci1);                                       \
        rv = t ? a1 : c1; riv = t ? ai1 : ci1;                                  \
        a1 = t ? a2 : a1;  ai1 = t ? ai2 : ai1;                                 \
        a2 = t ? a3 : a2;  ai2 = t ? ai3 : ai2;                                 \
        a3 = t ? a4 : a3;  ai3 = t ? ai4 : ai3;                                 \
        a4 = t ? a5 : a4;  ai4 = t ? 0x7FFFFFFF : ai4;                          \
        a5 = t ? FLT_MAX : a5;                                                  \
        c1 = t ? c1 : c2;  ci1 = t ? ci1 : ci2;                                 \
        c2 = t ? c2 : c3;  ci2 = t ? ci2 : ci3;                                 \
        c3 = t ? c3 : c4;  ci3 = t ? ci3 : ci4;                                 \
        c4 = t ? c4 : c5;  ci4 = t ? ci4 : 0x7FFFFFFF;                          \
        c5 = t ? c5 : FLT_MAX;                                                  \
    }

__device__ __forceinline__ void merge5(float& a1, int& ai1, float& a2, int& ai2,
                                       float& a3, int& ai3, float& a4, int& ai4, float& a5,
                                       float c1, int ci1, float c2, int ci2,
                                       float c3, int ci3, float c4, int ci4, float c5) {
    float r1, r2, r3, r4; int ri1, ri2, ri3, ri4;
    POPSTEP(r1, ri1)
    POPSTEP(r2, ri2)
    POPSTEP(r3, ri3)
    POPSTEP(r4, ri4)
    float r5 = fminf(a1, c1);
    a1 = r1; ai1 = ri1; a2 = r2; ai2 = ri2; a3 = r3; ai3 = ri3; a4 = r4; ai4 = ri4; a5 = r5;
}

// classify one row and emit idx / worklist entries (lanes<16, wave-aggregated atomics)
__device__ __forceinline__ void emit_row(float* out, int gidx, int lane,
                                         float B1, int I1, float B2, int I2,
                                         float B3, int I3, float B4, int I4, float B5) {
    bool act = (lane < 16);
    bool clean = act && (B2 > B1 + TAU);
    bool cand  = act && !clean && (B5 > B1 + TAU);
    bool full  = act && !clean && !cand;
    if (act) out[IDX_OFF + gidx] = (float)I1;      // final for clean; placeholder else
    unsigned* cnt = (unsigned*)(out + CNT_OFF);
    unsigned long long mc = __ballot(cand);
    if (mc) {
        int leader = __ffsll((long long)mc) - 1;
        unsigned base = 0;
        if (lane == leader) base = atomicAdd(cnt, (unsigned)__popcll(mc));
        base = __shfl(base, leader);
        if (cand) {
            unsigned pos = base + (unsigned)__popcll(mc & ((1ull << lane) - 1ull));
            reinterpret_cast<uint4*>(out + CAND_OFF)[pos] =
                make_uint4((unsigned)gidx,
                           (unsigned)I1 | ((unsigned)I2 << 16),
                           (unsigned)I3 | ((unsigned)I4 << 16), 0u);
        }
    }
    unsigned long long mf = __ballot(full);
    if (mf) {
        int leader = __ffsll((long long)mf) - 1;
        unsigned base = 0;
        if (lane == leader) base = atomicAdd(cnt + 1, (unsigned)__popcll(mf));
        base = __shfl(base, leader);
        if (full) {
            unsigned pos = base + (unsigned)__popcll(mf & ((1ull << lane) - 1ull));
            reinterpret_cast<unsigned*>(out + FULL_OFF)[pos] = (unsigned)gidx;
        }
    }
}

// ---- K1: fp16 MFMA fast pass, top-5. Block = 128 rows (4 waves x 32). ----
__global__ __launch_bounds__(256) void vq_fast(const float* __restrict__ z,
                                               float* __restrict__ out) {
    __shared__ uint4 etile[512];                   // 8KB, one 16-code tile of A-frags
    const int tid = threadIdx.x;
    const int wave = tid >> 6, lane = tid & 63;
    const int khi = lane >> 4, l16 = lane & 15;
    const int nbase = blockIdx.x * 128;
    const int b = nbase / MB;
    const int mbase = nbase % MB;
    const float* zb = z + (size_t)b * DIM * MB + mbase + wave * 32 + l16;

    // z B-fragments (fp16), 2 row-sets x 8 kc
    h8 zf0[8], zf1[8];
    #pragma unroll
    for (int kc = 0; kc < 8; ++kc) {
        h8 va, vb;
        #pragma unroll
        for (int j = 0; j < 8; ++j) {
            size_t off = (size_t)(kc * 32 + khi * 8 + j) * MB;
            va[j] = (_Float16)zb[off];
            vb[j] = (_Float16)zb[off + 16];
        }
        zf0[kc] = va; zf1[kc] = vb;
    }

    const uint4* ET = reinterpret_cast<const uint4*>(out);
    const float* Btab = out + BT_OFF;

    float b10 = FLT_MAX, b20 = FLT_MAX, b30 = FLT_MAX, b40 = FLT_MAX, b50 = FLT_MAX;
    float b11 = FLT_MAX, b21 = FLT_MAX, b31 = FLT_MAX, b41 = FLT_MAX, b51 = FLT_MAX;
    int i10 = 0, i20 = 0, i30 = 0, i40 = 0;
    int i11 = 0, i21 = 0, i31 = 0, i41 = 0;

    uint4 r0 = ET[tid], r1 = ET[tid + 256];        // preload tile 0

    for (int tile = 0; tile < KC / 16; ++tile) {
        etile[tid] = r0; etile[tid + 256] = r1;
        __syncthreads();
        if (tile < KC / 16 - 1) {
            r0 = ET[(tile + 1) * 512 + tid];
            r1 = ET[(tile + 1) * 512 + tid + 256];
        }

        f4v a0 = {0.f, 0.f, 0.f, 0.f}, a1 = a0;
        #pragma unroll
        for (int kc = 0; kc < 8; ++kc) {
            union { uint4 q; h8 v; } af;
            af.q = etile[kc * 64 + lane];
            a0 = __builtin_amdgcn_mfma_f32_16x16x32_f16(af.v, zf0[kc], a0, 0, 0, 0);
            a1 = __builtin_amdgcn_mfma_f32_16x16x32_f16(af.v, zf1[kc], a1, 0, 0, 0);
        }

        const f4v Bv = *reinterpret_cast<const f4v*>(Btab + tile * 16 + khi * 4);
        #pragma unroll
        for (int i = 0; i < 4; ++i) {
            int k = tile * 16 + khi * 4 + i;       // ascending per lane
            float s0 = fmaf(-4.8828125e-4f, a0[i], Bv[i]);  // -1/2048 exact
            float s1 = fmaf(-4.8828125e-4f, a1[i], Bv[i]);
            INS5(s0, k, b10, i10, b20, i20, b30, i30, b40, i40, b50)
            INS5(s1, k, b11, i11, b21, i21, b31, i31, b41, i41, b51)
        }
        __syncthreads();
    }

    // merge the 4 khi code-groups (lanes sharing l16 = same z-row)
    #pragma unroll
    for (int off = 16; off < 64; off <<= 1) {
        merge5(b10, i10, b20, i20, b30, i30, b40, i40, b50,
               __shfl_xor(b10, off), __shfl_xor(i10, off),
               __shfl_xor(b20, off), __shfl_xor(i20, off),
               __shfl_xor(b30, off), __shfl_xor(i30, off),
               __shfl_xor(b40, off), __shfl_xor(i40, off), __shfl_xor(b50, off));
        merge5(b11, i11, b21, i21, b31, i31, b41, i41, b51,
               __shfl_xor(b11, off), __shfl_xor(i11, off),
               __shfl_xor(b21, off), __shfl_xor(i21, off),
               __shfl_xor(b31, off), __shfl_xor(i31, off),
               __shfl_xor(b41, off), __shfl_xor(i41, off), __shfl_xor(b51, off));
    }
    emit_row(out, nbase + wave * 32 + l16, lane, b10, i10, b20, i20, b30, i30, b40, i40, b50);
    emit_row(out, nbase + wave * 32 + 16 + l16, lane, b11, i11, b21, i21, b31, i31, b41, i41, b51);
}

// ---- K2a: candidate rescore (<=4 codes), grid-stride waves over cand list ----
__global__ __launch_bounds__(256) void vq_resolve_cand(const float* __restrict__ z,
                                                       const float* __restrict__ e,
                                                       float* __restrict__ out) {
    const int wave = threadIdx.x >> 6, lane = threadIdx.x & 63;
    const unsigned n = *reinterpret_cast<const unsigned*>(out + CNT_OFF);
    const uint4* list = reinterpret_cast<const uint4*>(out + CAND_OFF);
    for (unsigned ei = blockIdx.x * 4 + wave; ei < n; ei += gridDim.x * 4) {
        uint4 ent = list[ei];
        const int gidx = (int)ent.x;
        const int c1 = (int)(ent.y & 0xFFFFu), c2 = (int)(ent.y >> 16);
        const int c3 = (int)(ent.z & 0xFFFFu), c4 = (int)(ent.z >> 16);
        const int b = gidx >> 14, m = gidx & (MB - 1);
        const float* zr = z + (size_t)b * DIM * MB + m;
        const float* e1 = e + (size_t)c1 * DIM;
        const float* e2 = e + (size_t)c2 * DIM;
        const float* e3 = e + (size_t)c3 * DIM;
        const float* e4 = e + (size_t)c4 * DIM;
        double A = 0.0;
        double d1 = 0.0, d2 = 0.0, d3 = 0.0, d4 = 0.0;
        double q1 = 0.0, q2 = 0.0, q3 = 0.0, q4 = 0.0;
        #pragma unroll
        for (int jj = 0; jj < 4; ++jj) {
            int d = lane * 4 + jj;
            double zv = (double)zr[(size_t)d * MB];
            double v1 = (double)e1[d], v2 = (double)e2[d];
            double v3 = (double)e3[d], v4 = (double)e4[d];
            A = fma(zv, zv, A);
            d1 = fma(zv, v1, d1); q1 = fma(v1, v1, q1);
            d2 = fma(zv, v2, d2); q2 = fma(v2, v2, q2);
            d3 = fma(zv, v3, d3); q3 = fma(v3, v3, q3);
            d4 = fma(zv, v4, d4); q4 = fma(v4, v4, q4);
        }
        #pragma unroll
        for (int mm = 1; mm < 64; mm <<= 1) {
            A += __shfl_xor(A, mm);
            d1 += __shfl_xor(d1, mm); q1 += __shfl_xor(q1, mm);
            d2 += __shfl_xor(d2, mm); q2 += __shfl_xor(q2, mm);
            d3 += __shfl_xor(d3, mm); q3 += __shfl_xor(q3, mm);
            d4 += __shfl_xor(d4, mm); q4 += __shfl_xor(q4, mm);
        }
        if (lane == 0) {
            float Af = (float)A;
            float s1 = (Af - (float)(2.0 * d1)) + (float)q1;
            float s2 = (Af - (float)(2.0 * d2)) + (float)q2;
            float s3 = (Af - (float)(2.0 * d3)) + (float)q3;
            float s4 = (Af - (float)(2.0 * d4)) + (float)q4;
            float bv = s1; int bk = c1;
            if (lexlt(s2, c2, bv, bk)) { bv = s2; bk = c2; }
            if (lexlt(s3, c3, bv, bk)) { bv = s3; bk = c3; }
            if (lexlt(s4, c4, bv, bk)) { bv = s4; bk = c4; }
            out[IDX_OFF + gidx] = (float)bk;
        }
    }
}

// ---- K2b: full exact rescan, grid-stride blocks over full list ----
__global__ __launch_bounds__(256) void vq_resolve_full(const float* __restrict__ z,
                                                       const float* __restrict__ e,
                                                       float* __restrict__ out) {
    __shared__ float zs[DIM];
    __shared__ float rv[4];
    __shared__ int ri[4];
    const int tid = threadIdx.x;
    const int wave = tid >> 6, lane = tid & 63;
    const unsigned n = reinterpret_cast<const unsigned*>(out + CNT_OFF)[1];
    const unsigned* list = reinterpret_cast<const unsigned*>(out + FULL_OFF);
    for (unsigned ei = blockIdx.x; ei < n; ei += gridDim.x) {
        const int gidx = (int)list[ei];
        const int b = gidx >> 14, m = gidx & (MB - 1);
        const float* zr = z + (size_t)b * DIM * MB + m;
        if (tid < DIM) zs[tid] = zr[(size_t)tid * MB];
        __syncthreads();
        double av = 0.0;
        #pragma unroll
        for (int t2 = 0; t2 < 4; ++t2) {
            double zv = (double)zs[lane * 4 + t2];
            av = fma(zv, zv, av);
        }
        #pragma unroll
        for (int mm = 1; mm < 64; mm <<= 1) av += __shfl_xor(av, mm);
        const float Af = (float)av;

        float bsv = FLT_MAX; int bsk = 0;
        for (int kk = 0; kk < 16; ++kk) {
            const int k = kk * 256 + tid;          // ascending per thread
            const float4* er4 = reinterpret_cast<const float4*>(e + (size_t)k * DIM);
            const float4* zs4 = reinterpret_cast<const float4*>(zs);
            double dot0 = 0.0, dot1 = 0.0, q0 = 0.0, q1 = 0.0;
            #pragma unroll 8
            for (int d4 = 0; d4 < 64; ++d4) {
                float4 ev = er4[d4];
                float4 zv = zs4[d4];
                dot0 = fma((double)zv.x, (double)ev.x, dot0);
                dot1 = fma((double)zv.y, (double)ev.y, dot1);
                dot0 = fma((double)zv.z, (double)ev.z, dot0);
                dot1 = fma((double)zv.w, (double)ev.w, dot1);
                q0 = fma((double)ev.x, (double)ev.x, q0);
                q1 = fma((double)ev.y, (double)ev.y, q1);
                q0 = fma((double)ev.z, (double)ev.z, q0);
                q1 = fma((double)ev.w, (double)ev.w, q1);
            }
            float s = (Af - (float)(2.0 * (dot0 + dot1))) + (float)(q0 + q1);
            if (s < bsv) { bsv = s; bsk = k; }
        }
        #pragma unroll
        for (int mm = 1; mm < 64; mm <<= 1) {
            float ov = __shfl_xor(bsv, mm);
            int oi = __shfl_xor(bsk, mm);
            if (ov < bsv || (ov == bsv && oi < bsk)) { bsv = ov; bsk = oi; }
        }
        if (lane == 0) { rv[wave] = bsv; ri[wave] = bsk; }
        __syncthreads();
        if (tid == 0) {
            float bv = rv[0]; int bk = ri[0];
            #pragma unroll
            for (int wv = 1; wv < 4; ++wv) {
                if (rv[wv] < bv || (rv[wv] == bv && ri[wv] < bk)) { bv = rv[wv]; bk = ri[wv]; }
            }
            out[IDX_OFF + gidx] = (float)bk;
        }
        __syncthreads();
    }
}

// ---- K3: z_q scatter + fused loss; e-rows staged in LDS (coalesced) ----
__global__ __launch_bounds__(256) void vq_apply(const float* __restrict__ z,
                                                const float* __restrict__ e,
                                                float* __restrict__ out) {
    __shared__ int lds_fi[64];
    __shared__ float lds_e[64][260];
    __shared__ double lds_ls[4];
    const int tid = threadIdx.x;
    const int wave = tid >> 6, lane = tid & 63;
    const int nbase = blockIdx.x * 64;
    const int b = nbase / MB;
    const int mbase = nbase % MB;
    if (tid < 64) lds_fi[tid] = (int)out[IDX_OFF + nbase + tid];
    __syncthreads();
    for (int r = wave; r < 64; r += 4) {
        int code = lds_fi[r];
        float4 v = reinterpret_cast<const float4*>(e + (size_t)code * DIM)[lane];
        *reinterpret_cast<float4*>(&lds_e[r][lane * 4]) = v;
    }
    __syncthreads();

    double lsum = 0.0;
    const int mloc = tid & 63;
    const int d0 = tid >> 6;
    #pragma unroll 4
    for (int d = d0; d < DIM; d += 4) {
        float ev = lds_e[mloc][d];
        size_t off = (size_t)b * (DIM * MB) + (size_t)d * MB + mbase + mloc;
        float zv = z[off];
        out[off] = ev;
        float diff = ev - zv;
        lsum += (double)diff * diff;
    }
    #pragma unroll
    for (int off = 32; off > 0; off >>= 1) lsum += __shfl_down(lsum, off);
    if (lane == 0) lds_ls[wave] = lsum;
    __syncthreads();
    if (tid == 0) {
        double t = lds_ls[0] + lds_ls[1] + lds_ls[2] + lds_ls[3];
        atomicAdd(out + LOSS_OFF, (float)(t * (1.25 / (double)ZELEMS)));
    }
}

extern "C" void kernel_launch(void* const* d_in, const int* in_sizes, int n_in,
                              void* d_out, int out_size, void* d_ws, size_t ws_size,
                              hipStream_t stream) {
    const float* z = (const float*)d_in[0];    // [4,256,16,32,32] fp32
    const float* e = (const float*)d_in[1];    // [4096,256] fp32
    float* out = (float*)d_out;

    hipMemsetAsync(out + LOSS_OFF, 0, sizeof(float), stream);
    hipMemsetAsync(out + CNT_OFF, 0, 2 * sizeof(unsigned), stream);
    vq_prep_b<<<KC / 4, 256, 0, stream>>>(e, out);
    vq_prep_e<<<512, 256, 0, stream>>>(e, out);
    vq_fast<<<NTOT / 128, 256, 0, stream>>>(z, out);
    vq_resolve_cand<<<256, 256, 0, stream>>>(z, e, out);
    vq_resolve_full<<<512, 256, 0, stream>>>(z, e, out);
    vq_apply<<<NTOT / 64, 256, 0, stream>>>(z, e, out);
}